// Round 11
// baseline (459.133 us; speedup 1.0000x reference)
//
#include <hip/hip_runtime.h>

// VariationalMPS R13: R11 skeleton + BLOCK-LEVEL CONTRACTION SPLIT (2x).
// Phase grids were < #CUs, so phase time = per-block serial time. Split the
// contraction axis across 2 blocks per tile: eA splits a (each block fuses its
// partial T1 with h2 -- linear -- writing T2part[ah]); eB splits k (writing
// Lpart[kh]). Partials are summed in the NEXT phase's staging reads (no extra
// dispatches): eB stages T2a+T2b, eA stages La+Lb, dot sums both L partials.
// Inner loops / microtiles / LDS sizes verbatim R11 (the proven 386us shapes).

#define D 128
#define W 8
#define NS 40
#define NPAIR 20
#define HALF2 10
#define MSZ (D * 2 * D)        // 32768
#define HSZ (W * W * 2 * 2)    // 256
#define M2SZ (D * 4 * D)       // 65536  [a][I][c] = a*512+I*128+c
#define H2SZ (W * W * 4 * 4)   // 1024   [w][x][I][J]
#define LSZ (D * W * D)        // 131072 [a][w][b] (= [p][x][q] after B)
#define NSZ (D * D)            // 16384
#define T2SZ (D * W * D * 4)   // 524288 row(p,x)*512 + b*4+J
#define TNSZ (4 * D * D)       // 65536  [I][p][b]

#define OFF_M2 0
#define OFF_MR2 (OFF_M2 + NPAIR * M2SZ)
#define OFF_H2 (OFF_MR2 + HALF2 * M2SZ)
#define OFF_HR2 (OFF_H2 + NPAIR * H2SZ)
#define OFF_L (OFF_HR2 + HALF2 * H2SZ)
#define LP(side, kh) (OFF_L + ((side) * 2 + (kh)) * LSZ)     // 4 L partials
#define OFF_N (OFF_L + 4 * LSZ)
#define OFF_NL OFF_N
#define OFF_NR (OFF_N + NSZ)
#define OFF_T2 (OFF_N + 2 * NSZ)
#define T2P(side, ah) (OFF_T2 + ((side) * 2 + (ah)) * T2SZ)  // 4 T2 partials
#define OFF_TN (OFF_T2 + 4 * T2SZ)
#define OFF_TNL OFF_TN
#define OFF_TNR (OFF_TN + TNSZ)
#define OFF_PART (OFF_TN + 2 * TNSZ)
#define OFF_PARTN (OFF_PART + 128)

// ---------------- prep1: pair GEMMs M2 (640 blocks) + H2 (block 640) --------
__global__ __launch_bounds__(256) void k_prep1(const float* __restrict__ Min,
                                               const float* __restrict__ Hin,
                                               float* __restrict__ ws) {
    __shared__ float As[32 * 34];
    __shared__ float Bs[32 * 68];
    int bid = blockIdx.x, t = threadIdx.x;
    if (bid < 640) {
        int m = bid >> 5, tile = bid & 31;
        int r0 = (tile & 7) * 32, c0 = (tile >> 3) * 64;
        const float* A = Min + (2 * m) * MSZ;
        const float* B = Min + (2 * m + 1) * MSZ;
        float* C = ws + OFF_M2 + m * M2SZ;
        int ty = t >> 4, tx = t & 15;
        float a00 = 0, a01 = 0, a02 = 0, a03 = 0;
        float a10 = 0, a11 = 0, a12 = 0, a13 = 0;
        for (int c = 0; c < 4; ++c) {
            int k0 = c * 32;
            __syncthreads();
            {
                int rr = t >> 3, kq = t & 7;
                int row = r0 + rr;
                const float4 v = *(const float4*)&A[(row >> 1) * 256 + (row & 1) * 128 + k0 + kq * 4];
                float* dst = &As[kq * 136 + rr];
                dst[0] = v.x; dst[34] = v.y; dst[68] = v.z; dst[102] = v.w;
            }
#pragma unroll
            for (int u = 0; u < 2; ++u) {
                int e = u * 256 + t;
                int kk = e >> 4, cq = e & 15;
                const float4 v = *(const float4*)&B[(k0 + kk) * 256 + c0 + cq * 4];
                *(float4*)&Bs[kk * 68 + cq * 4] = v;
            }
            __syncthreads();
#pragma unroll 8
            for (int kk = 0; kk < 32; ++kk) {
                float2 av = *(float2*)&As[kk * 34 + 2 * ty];
                float4 bv = *(float4*)&Bs[kk * 68 + 4 * tx];
                a00 += av.x * bv.x; a01 += av.x * bv.y; a02 += av.x * bv.z; a03 += av.x * bv.w;
                a10 += av.y * bv.x; a11 += av.y * bv.y; a12 += av.y * bv.z; a13 += av.y * bv.w;
            }
        }
        int r = r0 + 2 * ty, cc = c0 + 4 * tx;
        int a = r >> 1, i2 = cc >> 7, cd = cc & 127;
        float4 v0; v0.x = a00; v0.y = a01; v0.z = a02; v0.w = a03;
        float4 v1; v1.x = a10; v1.y = a11; v1.z = a12; v1.w = a13;
        *(float4*)&C[a * 512 + (0 * 2 + i2) * 128 + cd] = v0;
        *(float4*)&C[a * 512 + (1 * 2 + i2) * 128 + cd] = v1;
    } else {
        for (int idx = t; idx < NPAIR * H2SZ; idx += 256) {
            int m = idx >> 10, r = idx & 1023;
            int w = r >> 7, x = (r >> 4) & 7, I = (r >> 2) & 3, J = r & 3;
            int i1 = I >> 1, i2 = I & 1, j1 = J >> 1, j2 = J & 1;
            const float* Ha = Hin + (2 * m) * HSZ;
            const float* Hb = Hin + (2 * m + 1) * HSZ;
            float s = 0.f;
#pragma unroll
            for (int v = 0; v < 8; ++v)
                s += Ha[w * 32 + v * 4 + i1 * 2 + j1] * Hb[v * 32 + x * 4 + i2 * 2 + j2];
            ws[OFF_H2 + idx] = s;
        }
    }
}

// ---------------- prep2: rev transposes + env init --------------------------
#define PR_MR (HALF2 * M2SZ)
#define PR_HR (PR_MR + HALF2 * H2SZ)
#define PR_TOT (PR_HR + 4 * LSZ + 2 * NSZ)
__global__ __launch_bounds__(256) void k_prep2(float* __restrict__ ws) {
    for (int idx = blockIdx.x * 256 + threadIdx.x; idx < PR_TOT; idx += gridDim.x * 256) {
        if (idx < PR_MR) {
            int kr = idx >> 16, r = idx & 65535;
            int a = r >> 9, I = (r >> 7) & 3, p = r & 127;
            ws[OFF_MR2 + idx] = ws[OFF_M2 + (19 - kr) * M2SZ + p * 512 + I * 128 + a];
        } else if (idx < PR_HR) {
            int e = idx - PR_MR;
            int kr = e >> 10, r = e & 1023;
            int w = r >> 7, x = (r >> 4) & 7, lo = r & 15;
            ws[OFF_HR2 + e] = ws[OFF_H2 + (19 - kr) * H2SZ + x * 128 + w * 16 + lo];
        } else {
            int e = idx - PR_HR;
            int off; float v = 0.f;
            if (e < LSZ)            { off = LP(0, 0) + e; if (e == 0) v = 1.f; }
            else if (e < 2 * LSZ)   { off = LP(0, 1) + (e - LSZ); }            // zero
            else if (e < 3 * LSZ)   { int r = e - 2 * LSZ; off = LP(1, 0) + r; if (r == (W - 1) * D) v = 1.f; }
            else if (e < 4 * LSZ)   { off = LP(1, 1) + (e - 3 * LSZ); }        // zero
            else if (e < 4 * LSZ + NSZ) { int r = e - 4 * LSZ; off = OFF_NL + r; if (r == 0) v = 1.f; }
            else                    { int r = e - 4 * LSZ - NSZ; off = OFF_NR + r; if (r == 0) v = 1.f; }
            ws[off] = v;
        }
    }
}

// ---------------- phase A (512 threads, grid 288) ---------------------------
// Energy blocks 0..255: side = bid>>7, ah = (bid>>6)&1 splits the a-sum;
// stages L = La+Lb; R11 inner loop (z splits I, acc[8][2]); fuses its partial
// T1 with h2 and writes T2part[ah]. Norm blocks 256..287: R11 verbatim.
__global__ __launch_bounds__(512) void k_A2(float* __restrict__ ws, int k) {
    __shared__ __align__(16) float sm[9472];
    int bid = blockIdx.x, t = threadIdx.x;
    int z = t >> 8, tl = t & 255;
    if (bid < 256) {
        int side = bid >> 7;
        int e2 = bid & 127;
        int ah = e2 >> 6;
        int eb = e2 & 63;
        int b0 = (eb & 7) * 16;
        int p0 = (eb >> 3) * 16;
        const float* La = ws + LP(side, 0);
        const float* Lb = ws + LP(side, 1);
        const float* m2 = ws + (side ? OFF_MR2 : OFF_M2) + k * M2SZ;
        const float* h2 = ws + (side ? OFF_HR2 : OFF_H2) + k * H2SZ;
        float* T2 = ws + T2P(side, ah);
        float* Ls = sm;          // [32a][16b][12w-pad] stride 200 (6400)
        float* ms = sm + 6400;   // [32a][4I][16p] (2048)
        float* hs = sm + 8448;   // [32 wI][32 xJ] (1024)
#pragma unroll
        for (int u = 0; u < 2; ++u) {   // stage h2
            int e = u * 512 + t;
            int w = e >> 7, I = (e >> 5) & 3, x = (e >> 2) & 7, J = e & 3;
            hs[e] = h2[w * 128 + x * 16 + I * 4 + J];
        }
        int b_l = tl & 15, p_l = tl >> 4;
        float acc[8][2];
#pragma unroll
        for (int w = 0; w < 8; ++w) { acc[w][0] = 0.f; acc[w][1] = 0.f; }
        int e0 = t, e1 = 512 + t;
        int la0 = e0 >> 5, lw0 = (e0 >> 2) & 7, lb0 = e0 & 3;
        int la1 = e1 >> 5, lw1 = (e1 >> 2) & 7, lb1 = e1 & 3;
        int maa = t >> 4, mI = (t >> 2) & 3, mpq = t & 3;
        int abase = ah * 64;
        float4 pa0, pa1, pb0, pb1, pm;
        {
            int a0 = abase;
            pa0 = *(const float4*)&La[(a0 + la0) * 1024 + lw0 * 128 + b0 + lb0 * 4];
            pb0 = *(const float4*)&Lb[(a0 + la0) * 1024 + lw0 * 128 + b0 + lb0 * 4];
            pa1 = *(const float4*)&La[(a0 + la1) * 1024 + lw1 * 128 + b0 + lb1 * 4];
            pb1 = *(const float4*)&Lb[(a0 + la1) * 1024 + lw1 * 128 + b0 + lb1 * 4];
            pm = *(const float4*)&m2[(a0 + maa) * 512 + mI * 128 + p0 + mpq * 4];
        }
        for (int c = 0; c < 2; ++c) {
            __syncthreads();
            {
                float* d0 = &Ls[la0 * 200 + lb0 * 48 + lw0];
                d0[0] = pa0.x + pb0.x; d0[12] = pa0.y + pb0.y;
                d0[24] = pa0.z + pb0.z; d0[36] = pa0.w + pb0.w;
                float* d1 = &Ls[la1 * 200 + lb1 * 48 + lw1];
                d1[0] = pa1.x + pb1.x; d1[12] = pa1.y + pb1.y;
                d1[24] = pa1.z + pb1.z; d1[36] = pa1.w + pb1.w;
                *(float4*)&ms[maa * 64 + mI * 16 + mpq * 4] = pm;
            }
            if (c == 0) {
                int a0 = abase + 32;
                pa0 = *(const float4*)&La[(a0 + la0) * 1024 + lw0 * 128 + b0 + lb0 * 4];
                pb0 = *(const float4*)&Lb[(a0 + la0) * 1024 + lw0 * 128 + b0 + lb0 * 4];
                pa1 = *(const float4*)&La[(a0 + la1) * 1024 + lw1 * 128 + b0 + lb1 * 4];
                pb1 = *(const float4*)&Lb[(a0 + la1) * 1024 + lw1 * 128 + b0 + lb1 * 4];
                pm = *(const float4*)&m2[(a0 + maa) * 512 + mI * 128 + p0 + mpq * 4];
            }
            __syncthreads();
#pragma unroll 4
            for (int aa = 0; aa < 32; ++aa) {
                float4 l0 = *(float4*)&Ls[aa * 200 + b_l * 12];
                float4 l1 = *(float4*)&Ls[aa * 200 + b_l * 12 + 4];
                float lw[8] = {l0.x, l0.y, l0.z, l0.w, l1.x, l1.y, l1.z, l1.w};
                float mv0 = ms[aa * 64 + (2 * z) * 16 + p_l];
                float mv1 = ms[aa * 64 + (2 * z + 1) * 16 + p_l];
#pragma unroll
                for (int w = 0; w < 8; ++w) {
                    acc[w][0] += lw[w] * mv0;
                    acc[w][1] += lw[w] * mv1;
                }
            }
        }
        // fuse partial (this z's 16 wI), then z1->z0 reduce + store
        float o[32];
#pragma unroll
        for (int xJ = 0; xJ < 32; ++xJ) o[xJ] = 0.f;
#pragma unroll
        for (int w = 0; w < 8; ++w)
#pragma unroll
            for (int ii = 0; ii < 2; ++ii) {
                float tv = acc[w][ii];
                int wI = w * 4 + 2 * z + ii;
#pragma unroll
                for (int xJ = 0; xJ < 32; ++xJ) o[xJ] += tv * hs[wI * 32 + xJ];
            }
        __syncthreads();
        if (z == 1) {
#pragma unroll
            for (int j = 0; j < 8; ++j) {
                float4 v; v.x = o[j * 4]; v.y = o[j * 4 + 1];
                v.z = o[j * 4 + 2]; v.w = o[j * 4 + 3];
                *(float4*)&sm[tl * 32 + j * 4] = v;
            }
        }
        __syncthreads();
        if (z == 0) {
#pragma unroll
            for (int j = 0; j < 32; ++j) o[j] += sm[tl * 32 + j];
            int b = b0 + b_l, p = p0 + p_l;
#pragma unroll
            for (int x = 0; x < 8; ++x) {
                float4 v; v.x = o[x * 4]; v.y = o[x * 4 + 1];
                v.z = o[x * 4 + 2]; v.w = o[x * 4 + 3];
                *(float4*)&T2[p * 4096 + x * 512 + b * 4] = v;
            }
        }
    } else {
        int g = (bid - 256) * 2 + z;     // 0..63 (R11 norm A verbatim)
        int side = g >> 5;
        int nn = g & 31;
        int b0 = (nn & 3) * 32;
        int c0 = (nn >> 2) * 64;
        const float* Nsrc = ws + (side ? OFF_NR : OFF_NL);
        const float* m2 = ws + (side ? OFF_MR2 : OFF_M2) + k * M2SZ;
        float* Tn = ws + (side ? OFF_TNR : OFF_TNL);
        float* As = sm + z * 3264;
        float* Bs = sm + z * 3264 + 1056;
        int ty = tl >> 4, tx = tl & 15;
        float a00 = 0, a01 = 0, a02 = 0, a03 = 0;
        float a10 = 0, a11 = 0, a12 = 0, a13 = 0;
        for (int c = 0; c < 4; ++c) {
            int a0 = c * 32;
            __syncthreads();
#pragma unroll
            for (int u = 0; u < 4; ++u) {
                int e = u * 256 + tl;
                int kk = e >> 5, col = e & 31;
                As[kk * 33 + col] = Nsrc[(a0 + kk) * 128 + b0 + col];
            }
#pragma unroll
            for (int u = 0; u < 8; ++u) {
                int e = u * 256 + tl;
                int kk = e >> 6, col = e & 63;
                Bs[kk * 68 + col] = m2[(a0 + kk) * 512 + c0 + col];
            }
            __syncthreads();
#pragma unroll 8
            for (int kk = 0; kk < 32; ++kk) {
                float av0 = As[kk * 33 + 2 * ty], av1 = As[kk * 33 + 2 * ty + 1];
                float4 bv = *(float4*)&Bs[kk * 68 + 4 * tx];
                a00 += av0 * bv.x; a01 += av0 * bv.y; a02 += av0 * bv.z; a03 += av0 * bv.w;
                a10 += av1 * bv.x; a11 += av1 * bv.y; a12 += av1 * bv.z; a13 += av1 * bv.w;
            }
        }
        int b_ = b0 + 2 * ty;
        float rowv[2][4] = {{a00, a01, a02, a03}, {a10, a11, a12, a13}};
#pragma unroll
        for (int jj = 0; jj < 4; ++jj) {
            int col = c0 + 4 * tx + jj;
            int I = col >> 7, p = col & 127;
            Tn[I * 16384 + p * 128 + b_] = rowv[0][jj];
            Tn[I * 16384 + p * 128 + b_ + 1] = rowv[1][jj];
        }
    }
}

// ---------------- phase B (512 threads, grid 272) ---------------------------
// Energy blocks 0..255: side = bid>>7, kh = (bid>>6)&1 splits k; stages
// A = T2a+T2b; R11 inner loop (z 2-way k-split -> 4 chunks each);
// writes Lpart[kh]. Norm blocks 256..271: R11 verbatim.
__global__ __launch_bounds__(512) void k_B2(float* __restrict__ ws, int k) {
    __shared__ __align__(16) float sm[8576];
    int bid = blockIdx.x, t = threadIdx.x;
    int z = t >> 8, tl = t & 255;
    int ty = tl >> 4, tx = tl & 15;
    float a00 = 0, a01 = 0, a02 = 0, a03 = 0;
    float a10 = 0, a11 = 0, a12 = 0, a13 = 0;
    float* As = sm + z * 3264;        // [32][34] = 1088
    float* Bs = sm + z * 3264 + 1088; // [32][68] = 2176
    float* red = sm + 6528;           // 2048
    if (bid < 256) {
        int side = bid >> 7;
        int e2 = bid & 127;
        int kh = e2 >> 6;
        int eb = e2 & 63;
        int r0 = (eb & 31) * 32;
        int c0 = (eb >> 5) * 64;
        const float* Aa = ws + T2P(side, 0);
        const float* Ab = ws + T2P(side, 1);
        const float* B = ws + (side ? OFF_MR2 : OFF_M2) + k * M2SZ;
        float* C = ws + LP(side, kh);
        int rr = tl >> 3, kq = tl & 7;
        int kkb0 = tl >> 4, cq0 = tl & 15;
        int kkb1 = (256 + tl) >> 4, cq1 = tl & 15;
        int cbase = kh * 8 + z * 4;          // this (kh,z)'s 4 chunks
        int k0 = cbase * 32;
        float4 paa = *(const float4*)&Aa[(r0 + rr) * 512 + k0 + kq * 4];
        float4 pab = *(const float4*)&Ab[(r0 + rr) * 512 + k0 + kq * 4];
        int row0 = k0 + kkb0, row1 = k0 + kkb1;
        float4 pb0 = *(const float4*)&B[(row0 >> 2) * 512 + (row0 & 3) * 128 + c0 + cq0 * 4];
        float4 pb1 = *(const float4*)&B[(row1 >> 2) * 512 + (row1 & 3) * 128 + c0 + cq1 * 4];
        for (int c = 0; c < 4; ++c) {
            __syncthreads();
            {
                float* dst = &As[kq * 136 + rr];
                dst[0] = paa.x + pab.x; dst[34] = paa.y + pab.y;
                dst[68] = paa.z + pab.z; dst[102] = paa.w + pab.w;
                *(float4*)&Bs[kkb0 * 68 + cq0 * 4] = pb0;
                *(float4*)&Bs[kkb1 * 68 + cq1 * 4] = pb1;
            }
            if (c < 3) {
                int kn = (cbase + c + 1) * 32;
                paa = *(const float4*)&Aa[(r0 + rr) * 512 + kn + kq * 4];
                pab = *(const float4*)&Ab[(r0 + rr) * 512 + kn + kq * 4];
                int r0n = kn + kkb0, r1n = kn + kkb1;
                pb0 = *(const float4*)&B[(r0n >> 2) * 512 + (r0n & 3) * 128 + c0 + cq0 * 4];
                pb1 = *(const float4*)&B[(r1n >> 2) * 512 + (r1n & 3) * 128 + c0 + cq1 * 4];
            }
            __syncthreads();
#pragma unroll 8
            for (int kk = 0; kk < 32; ++kk) {
                float av0 = As[kk * 34 + 2 * ty], av1 = As[kk * 34 + 2 * ty + 1];
                float4 bv = *(float4*)&Bs[kk * 68 + 4 * tx];
                a00 += av0 * bv.x; a01 += av0 * bv.y; a02 += av0 * bv.z; a03 += av0 * bv.w;
                a10 += av1 * bv.x; a11 += av1 * bv.y; a12 += av1 * bv.z; a13 += av1 * bv.w;
            }
        }
        __syncthreads();
        if (z == 1) {
            float4 v0; v0.x = a00; v0.y = a01; v0.z = a02; v0.w = a03;
            float4 v1; v1.x = a10; v1.y = a11; v1.z = a12; v1.w = a13;
            *(float4*)&red[tl * 8] = v0;
            *(float4*)&red[tl * 8 + 4] = v1;
        }
        __syncthreads();
        if (z == 0) {
            float4 v0 = *(float4*)&red[tl * 8];
            float4 v1 = *(float4*)&red[tl * 8 + 4];
            a00 += v0.x; a01 += v0.y; a02 += v0.z; a03 += v0.w;
            a10 += v1.x; a11 += v1.y; a12 += v1.z; a13 += v1.w;
            int r = r0 + 2 * ty, cc = c0 + 4 * tx;
            float4 w0; w0.x = a00; w0.y = a01; w0.z = a02; w0.w = a03;
            float4 w1; w1.x = a10; w1.y = a11; w1.z = a12; w1.w = a13;
            *(float4*)&C[(r >> 3) * 1024 + (r & 7) * 128 + cc] = w0;
            *(float4*)&C[((r + 1) >> 3) * 1024 + ((r + 1) & 7) * 128 + cc] = w1;
        }
    } else if (bid < 272) {
        int g = bid - 256;               // R11 norm B verbatim
        int side = g >> 3;
        int nn = g & 7;
        int r0 = (nn & 3) * 32;
        int c0 = (nn >> 2) * 64;
        const float* A = ws + (side ? OFF_TNR : OFF_TNL);
        const float* B = ws + (side ? OFF_MR2 : OFF_M2) + k * M2SZ;
        float* C = ws + (side ? OFF_NR : OFF_NL);
        for (int c = 0; c < 8; ++c) {
            int cg = z * 8 + c;
            int Ic = cg >> 2, bc = (cg & 3) * 32;
            __syncthreads();
            {
                int rr = tl >> 3, kq = tl & 7;
                const float4 v = *(const float4*)&A[Ic * 16384 + (r0 + rr) * 128 + bc + kq * 4];
                float* dst = &As[kq * 136 + rr];
                dst[0] = v.x; dst[34] = v.y; dst[68] = v.z; dst[102] = v.w;
            }
#pragma unroll
            for (int u = 0; u < 2; ++u) {
                int e = u * 256 + tl;
                int kk = e >> 4, cq = e & 15;
                const float4 v = *(const float4*)&B[(bc + kk) * 512 + Ic * 128 + c0 + cq * 4];
                *(float4*)&Bs[kk * 68 + cq * 4] = v;
            }
            __syncthreads();
#pragma unroll 8
            for (int kk = 0; kk < 32; ++kk) {
                float av0 = As[kk * 34 + 2 * ty], av1 = As[kk * 34 + 2 * ty + 1];
                float4 bv = *(float4*)&Bs[kk * 68 + 4 * tx];
                a00 += av0 * bv.x; a01 += av0 * bv.y; a02 += av0 * bv.z; a03 += av0 * bv.w;
                a10 += av1 * bv.x; a11 += av1 * bv.y; a12 += av1 * bv.z; a13 += av1 * bv.w;
            }
        }
        __syncthreads();
        if (z == 1) {
            float4 v0; v0.x = a00; v0.y = a01; v0.z = a02; v0.w = a03;
            float4 v1; v1.x = a10; v1.y = a11; v1.z = a12; v1.w = a13;
            *(float4*)&red[tl * 8] = v0;
            *(float4*)&red[tl * 8 + 4] = v1;
        }
        __syncthreads();
        if (z == 0) {
            float4 v0 = *(float4*)&red[tl * 8];
            float4 v1 = *(float4*)&red[tl * 8 + 4];
            a00 += v0.x; a01 += v0.y; a02 += v0.z; a03 += v0.w;
            a10 += v1.x; a11 += v1.y; a12 += v1.z; a13 += v1.w;
            int r = r0 + 2 * ty, cc = c0 + 4 * tx;
            float4 w0; w0.x = a00; w0.y = a01; w0.z = a02; w0.w = a03;
            float4 w1; w1.x = a10; w1.y = a11; w1.z = a12; w1.w = a13;
            *(float4*)&C[r * 128 + cc] = w0;
            *(float4*)&C[(r + 1) * 128 + cc] = w1;
        }
    }
}

// ---------------- dot partials + loss ---------------------------------------
__global__ __launch_bounds__(256) void k_dot(float* __restrict__ ws) {
    __shared__ float se[256], sn[256];
    int bid = blockIdx.x, t = threadIdx.x;
    const float* LLa = ws + LP(0, 0);
    const float* LLb = ws + LP(0, 1);
    const float* LRa = ws + LP(1, 0);
    const float* LRb = ws + LP(1, 1);
    float e = 0.f;
#pragma unroll
    for (int u = 0; u < 4; ++u) {
        int i = bid * 1024 + u * 256 + t;
        e += (LLa[i] + LLb[i]) * (LRa[i] + LRb[i]);
    }
    float n = 0.f;
    if (t < 128) {
        int i = bid * 128 + t;
        n = ws[OFF_NL + i] * ws[OFF_NR + i];
    }
    se[t] = e;
    sn[t] = n;
    __syncthreads();
    for (int s = 128; s > 0; s >>= 1) {
        if (t < s) { se[t] += se[t + s]; sn[t] += sn[t + s]; }
        __syncthreads();
    }
    if (t == 0) {
        ws[OFF_PART + bid] = se[0];
        ws[OFF_PARTN + bid] = sn[0];
    }
}

__global__ __launch_bounds__(256) void k_loss(const float* __restrict__ ws,
                                              float* __restrict__ out) {
    __shared__ float se[128], sn[128];
    int t = threadIdx.x;
    if (t < 128) {
        se[t] = ws[OFF_PART + t];
        sn[t] = ws[OFF_PARTN + t];
    }
    __syncthreads();
    for (int s = 64; s > 0; s >>= 1) {
        if (t < s) { se[t] += se[t + s]; sn[t] += sn[t + s]; }
        __syncthreads();
    }
    if (t == 0) {
        float E = se[0], Nm = sn[0];
        out[0] = E;
        out[1] = Nm;
        out[2] = E / Nm;
        out[3] = fmaxf(Nm - 10000.0f, 0.0f);
    }
}

extern "C" void kernel_launch(void* const* d_in, const int* in_sizes, int n_in,
                              void* d_out, int out_size, void* d_ws, size_t ws_size,
                              hipStream_t stream) {
    const float* Min = (const float*)d_in[0];
    const float* Hin = (const float*)d_in[1];
    float* ws = (float*)d_ws;
    float* out = (float*)d_out;
    (void)in_sizes; (void)n_in; (void)out_size; (void)ws_size;

    k_prep1<<<dim3(641), dim3(256), 0, stream>>>(Min, Hin, ws);
    k_prep2<<<dim3(640), dim3(256), 0, stream>>>(ws);
    for (int k = 0; k < HALF2; ++k) {
        k_A2<<<dim3(288), dim3(512), 0, stream>>>(ws, k);
        k_B2<<<dim3(272), dim3(512), 0, stream>>>(ws, k);
    }
    k_dot<<<dim3(128), dim3(256), 0, stream>>>(ws);
    k_loss<<<dim3(1), dim3(256), 0, stream>>>(ws, out);
}

// Round 12
// 387.616 us; speedup vs baseline: 1.1845x; 1.1845x over previous
//
#include <hip/hip_runtime.h>

// VariationalMPS R14: R11 skeleton (proven 386us) with ONLY the energy-A inner
// loop replaced by R12's LDS-efficient version (which passed correctness in
// R12; R12's regression was isolated to its k_B2 rewrite, not eA).
//  eA: acc[8][4] per thread (32 FMAs per 3x ds_read_b128; ms relaid [aa][p][I]);
//      z splits the a-sum (2 chunks each), one LDS partial reduce at the end.
//  eB, norm paths, preps, dot, loss: R11 verbatim.

#define D 128
#define W 8
#define NS 40
#define NPAIR 20
#define HALF2 10
#define MSZ (D * 2 * D)        // 32768
#define HSZ (W * W * 2 * 2)    // 256
#define M2SZ (D * 4 * D)       // 65536  [a][I][c] = a*512+I*128+c
#define H2SZ (W * W * 4 * 4)   // 1024   [w][x][I][J]
#define LSZ (D * W * D)        // 131072 [a][w][b] (= [p][x][q] after B)
#define NSZ (D * D)            // 16384
#define T2SZ (D * W * D * 4)   // 524288 row(p,x)*512 + b*4+J
#define TNSZ (4 * D * D)       // 65536  [I][p][b]

#define OFF_M2 0
#define OFF_MR2 (OFF_M2 + NPAIR * M2SZ)
#define OFF_H2 (OFF_MR2 + HALF2 * M2SZ)
#define OFF_HR2 (OFF_H2 + NPAIR * H2SZ)
#define OFF_LL (OFF_HR2 + HALF2 * H2SZ)
#define OFF_LR (OFF_LL + LSZ)
#define OFF_NL (OFF_LR + LSZ)
#define OFF_NR (OFF_NL + NSZ)
#define OFF_T2L (OFF_NR + NSZ)
#define OFF_T2R (OFF_T2L + T2SZ)
#define OFF_TNL (OFF_T2R + T2SZ)
#define OFF_TNR (OFF_TNL + TNSZ)
#define OFF_PART (OFF_TNR + TNSZ)
#define OFF_PARTN (OFF_PART + 128)

// ---------------- prep1: pair GEMMs M2 (640 blocks) + H2 (block 640) --------
__global__ __launch_bounds__(256) void k_prep1(const float* __restrict__ Min,
                                               const float* __restrict__ Hin,
                                               float* __restrict__ ws) {
    __shared__ float As[32 * 34];
    __shared__ float Bs[32 * 68];
    int bid = blockIdx.x, t = threadIdx.x;
    if (bid < 640) {
        int m = bid >> 5, tile = bid & 31;
        int r0 = (tile & 7) * 32, c0 = (tile >> 3) * 64;
        const float* A = Min + (2 * m) * MSZ;
        const float* B = Min + (2 * m + 1) * MSZ;
        float* C = ws + OFF_M2 + m * M2SZ;
        int ty = t >> 4, tx = t & 15;
        float a00 = 0, a01 = 0, a02 = 0, a03 = 0;
        float a10 = 0, a11 = 0, a12 = 0, a13 = 0;
        for (int c = 0; c < 4; ++c) {
            int k0 = c * 32;
            __syncthreads();
            {
                int rr = t >> 3, kq = t & 7;
                int row = r0 + rr;
                const float4 v = *(const float4*)&A[(row >> 1) * 256 + (row & 1) * 128 + k0 + kq * 4];
                float* dst = &As[kq * 136 + rr];
                dst[0] = v.x; dst[34] = v.y; dst[68] = v.z; dst[102] = v.w;
            }
#pragma unroll
            for (int u = 0; u < 2; ++u) {
                int e = u * 256 + t;
                int kk = e >> 4, cq = e & 15;
                const float4 v = *(const float4*)&B[(k0 + kk) * 256 + c0 + cq * 4];
                *(float4*)&Bs[kk * 68 + cq * 4] = v;
            }
            __syncthreads();
#pragma unroll 8
            for (int kk = 0; kk < 32; ++kk) {
                float2 av = *(float2*)&As[kk * 34 + 2 * ty];
                float4 bv = *(float4*)&Bs[kk * 68 + 4 * tx];
                a00 += av.x * bv.x; a01 += av.x * bv.y; a02 += av.x * bv.z; a03 += av.x * bv.w;
                a10 += av.y * bv.x; a11 += av.y * bv.y; a12 += av.y * bv.z; a13 += av.y * bv.w;
            }
        }
        int r = r0 + 2 * ty, cc = c0 + 4 * tx;
        int a = r >> 1, i2 = cc >> 7, cd = cc & 127;
        float4 v0; v0.x = a00; v0.y = a01; v0.z = a02; v0.w = a03;
        float4 v1; v1.x = a10; v1.y = a11; v1.z = a12; v1.w = a13;
        *(float4*)&C[a * 512 + (0 * 2 + i2) * 128 + cd] = v0;
        *(float4*)&C[a * 512 + (1 * 2 + i2) * 128 + cd] = v1;
    } else {
        for (int idx = t; idx < NPAIR * H2SZ; idx += 256) {
            int m = idx >> 10, r = idx & 1023;
            int w = r >> 7, x = (r >> 4) & 7, I = (r >> 2) & 3, J = r & 3;
            int i1 = I >> 1, i2 = I & 1, j1 = J >> 1, j2 = J & 1;
            const float* Ha = Hin + (2 * m) * HSZ;
            const float* Hb = Hin + (2 * m + 1) * HSZ;
            float s = 0.f;
#pragma unroll
            for (int v = 0; v < 8; ++v)
                s += Ha[w * 32 + v * 4 + i1 * 2 + j1] * Hb[v * 32 + x * 4 + i2 * 2 + j2];
            ws[OFF_H2 + idx] = s;
        }
    }
}

// ---------------- prep2: rev transposes + env init --------------------------
#define PR_MR (HALF2 * M2SZ)
#define PR_HR (PR_MR + HALF2 * H2SZ)
#define PR_TOT (PR_HR + 2 * LSZ + 2 * NSZ)
__global__ __launch_bounds__(256) void k_prep2(float* __restrict__ ws) {
    for (int idx = blockIdx.x * 256 + threadIdx.x; idx < PR_TOT; idx += gridDim.x * 256) {
        if (idx < PR_MR) {
            int kr = idx >> 16, r = idx & 65535;
            int a = r >> 9, I = (r >> 7) & 3, p = r & 127;
            ws[OFF_MR2 + idx] = ws[OFF_M2 + (19 - kr) * M2SZ + p * 512 + I * 128 + a];
        } else if (idx < PR_HR) {
            int e = idx - PR_MR;
            int kr = e >> 10, r = e & 1023;
            int w = r >> 7, x = (r >> 4) & 7, lo = r & 15;
            ws[OFF_HR2 + e] = ws[OFF_H2 + (19 - kr) * H2SZ + x * 128 + w * 16 + lo];
        } else {
            int e = idx - PR_HR;
            int off; float v = 0.f;
            if (e < LSZ)            { off = OFF_LL + e; if (e == 0) v = 1.f; }
            else if (e < 2 * LSZ)   { int r = e - LSZ; off = OFF_LR + r; if (r == (W - 1) * D) v = 1.f; }
            else if (e < 2 * LSZ + NSZ) { int r = e - 2 * LSZ; off = OFF_NL + r; if (r == 0) v = 1.f; }
            else                    { int r = e - 2 * LSZ - NSZ; off = OFF_NR + r; if (r == 0) v = 1.f; }
            ws[off] = v;
        }
    }
}

// ---------------- phase A (512 threads, grid 160) ---------------------------
// Energy blocks 0..127 (R12's verified eA): thread = (b_l,p_l), acc[8w][4I];
// z splits a (z=0: 0..63, z=1: 64..127), LDS reduce, z0 fuses h2 + stores.
// Norm blocks 128..159: z = independent task (R11 verbatim).
__global__ __launch_bounds__(512) void k_A2(float* __restrict__ ws, int k) {
    __shared__ __align__(16) float sm[17920];
    int bid = blockIdx.x, t = threadIdx.x;
    int z = t >> 8, tl = t & 255;
    if (bid < 128) {
        int side = bid >> 6;
        int eb = bid & 63;
        int b0 = (eb & 7) * 16;
        int p0 = (eb >> 3) * 16;
        const float* Lsrc = ws + (side ? OFF_LR : OFF_LL);
        const float* m2 = ws + (side ? OFF_MR2 : OFF_M2) + k * M2SZ;
        const float* h2 = ws + (side ? OFF_HR2 : OFF_H2) + k * H2SZ;
        float* T2 = ws + (side ? OFF_T2R : OFF_T2L);
        float* Ls = sm + z * 6400;         // [32a][16b][12w-pad] stride 200
        float* ms = sm + 12800 + z * 2048; // [32a][16p][4I]
        float* hs = sm + 16896;            // [32 wI][32 xJ]
#pragma unroll
        for (int u = 0; u < 2; ++u) {   // stage h2
            int e = u * 512 + t;
            int w = e >> 7, I = (e >> 5) & 3, x = (e >> 2) & 7, J = e & 3;
            hs[e] = h2[w * 128 + x * 16 + I * 4 + J];
        }
        int b_l = tl & 15, p_l = tl >> 4;
        float acc[8][4];
#pragma unroll
        for (int w = 0; w < 8; ++w)
#pragma unroll
            for (int I = 0; I < 4; ++I) acc[w][I] = 0.f;
        int la[4], lw[4], lb[4], maa[2], mI[2], mpq[2];
#pragma unroll
        for (int u = 0; u < 4; ++u) {
            int e = u * 256 + tl;
            la[u] = e >> 5; lw[u] = (e >> 2) & 7; lb[u] = e & 3;
        }
#pragma unroll
        for (int u = 0; u < 2; ++u) {
            int e = u * 256 + tl;
            maa[u] = e >> 4; mI[u] = (e >> 2) & 3; mpq[u] = e & 3;
        }
        float4 pl[4], pm[2];
        {
            int a0 = z * 64;
#pragma unroll
            for (int u = 0; u < 4; ++u)
                pl[u] = *(const float4*)&Lsrc[(a0 + la[u]) * 1024 + lw[u] * 128 + b0 + lb[u] * 4];
#pragma unroll
            for (int u = 0; u < 2; ++u)
                pm[u] = *(const float4*)&m2[(a0 + maa[u]) * 512 + mI[u] * 128 + p0 + mpq[u] * 4];
        }
        for (int c = 0; c < 2; ++c) {
            __syncthreads();
#pragma unroll
            for (int u = 0; u < 4; ++u) {
                float* dst = &Ls[la[u] * 200 + lb[u] * 48 + lw[u]];
                dst[0] = pl[u].x; dst[12] = pl[u].y; dst[24] = pl[u].z; dst[36] = pl[u].w;
            }
#pragma unroll
            for (int u = 0; u < 2; ++u) {   // ms[aa][p][I]: scatter over p
                int base = maa[u] * 64 + mpq[u] * 16 + mI[u];
                ms[base] = pm[u].x; ms[base + 4] = pm[u].y;
                ms[base + 8] = pm[u].z; ms[base + 12] = pm[u].w;
            }
            if (c == 0) {
                int a0 = z * 64 + 32;
#pragma unroll
                for (int u = 0; u < 4; ++u)
                    pl[u] = *(const float4*)&Lsrc[(a0 + la[u]) * 1024 + lw[u] * 128 + b0 + lb[u] * 4];
#pragma unroll
                for (int u = 0; u < 2; ++u)
                    pm[u] = *(const float4*)&m2[(a0 + maa[u]) * 512 + mI[u] * 128 + p0 + mpq[u] * 4];
            }
            __syncthreads();
#pragma unroll 4
            for (int aa = 0; aa < 32; ++aa) {
                float4 l0 = *(float4*)&Ls[aa * 200 + b_l * 12];
                float4 l1 = *(float4*)&Ls[aa * 200 + b_l * 12 + 4];
                float4 mv = *(float4*)&ms[aa * 64 + p_l * 4];
                float lv[8] = {l0.x, l0.y, l0.z, l0.w, l1.x, l1.y, l1.z, l1.w};
#pragma unroll
                for (int w = 0; w < 8; ++w) {
                    acc[w][0] += lv[w] * mv.x;
                    acc[w][1] += lv[w] * mv.y;
                    acc[w][2] += lv[w] * mv.z;
                    acc[w][3] += lv[w] * mv.w;
                }
            }
        }
        // reduce z1 -> z0 (red aliases Ls region, dead after sync)
        __syncthreads();
        float* red = sm;
        if (z == 1) {
#pragma unroll
            for (int w = 0; w < 8; ++w) {
                float4 v; v.x = acc[w][0]; v.y = acc[w][1]; v.z = acc[w][2]; v.w = acc[w][3];
                *(float4*)&red[tl * 32 + w * 4] = v;
            }
        }
        __syncthreads();
        if (z == 0) {
#pragma unroll
            for (int w = 0; w < 8; ++w) {
                float4 v = *(float4*)&red[tl * 32 + w * 4];
                acc[w][0] += v.x; acc[w][1] += v.y; acc[w][2] += v.z; acc[w][3] += v.w;
            }
            float o[32];
#pragma unroll
            for (int xJ = 0; xJ < 32; ++xJ) o[xJ] = 0.f;
#pragma unroll
            for (int wI = 0; wI < 32; ++wI) {
                float tv = acc[wI >> 2][wI & 3];
#pragma unroll
                for (int xJ = 0; xJ < 32; ++xJ) o[xJ] += tv * hs[wI * 32 + xJ];
            }
            int b = b0 + b_l, p = p0 + p_l;
#pragma unroll
            for (int x = 0; x < 8; ++x) {
                float4 v; v.x = o[x * 4]; v.y = o[x * 4 + 1];
                v.z = o[x * 4 + 2]; v.w = o[x * 4 + 3];
                *(float4*)&T2[p * 4096 + x * 512 + b * 4] = v;
            }
        }
    } else {
        int g = (bid - 128) * 2 + z;     // 0..63 (R11 norm A verbatim)
        int side = g >> 5;
        int nn = g & 31;
        int b0 = (nn & 3) * 32;
        int c0 = (nn >> 2) * 64;
        const float* Nsrc = ws + (side ? OFF_NR : OFF_NL);
        const float* m2 = ws + (side ? OFF_MR2 : OFF_M2) + k * M2SZ;
        float* Tn = ws + (side ? OFF_TNR : OFF_TNL);
        float* As = sm + z * 3264;       // [32][33]
        float* Bs = sm + z * 3264 + 1056; // [32][68]
        int ty = tl >> 4, tx = tl & 15;
        float a00 = 0, a01 = 0, a02 = 0, a03 = 0;
        float a10 = 0, a11 = 0, a12 = 0, a13 = 0;
        for (int c = 0; c < 4; ++c) {
            int a0 = c * 32;
            __syncthreads();
#pragma unroll
            for (int u = 0; u < 4; ++u) {
                int e = u * 256 + tl;
                int kk = e >> 5, col = e & 31;
                As[kk * 33 + col] = Nsrc[(a0 + kk) * 128 + b0 + col];
            }
#pragma unroll
            for (int u = 0; u < 8; ++u) {
                int e = u * 256 + tl;
                int kk = e >> 6, col = e & 63;
                Bs[kk * 68 + col] = m2[(a0 + kk) * 512 + c0 + col];
            }
            __syncthreads();
#pragma unroll 8
            for (int kk = 0; kk < 32; ++kk) {
                float av0 = As[kk * 33 + 2 * ty], av1 = As[kk * 33 + 2 * ty + 1];
                float4 bv = *(float4*)&Bs[kk * 68 + 4 * tx];
                a00 += av0 * bv.x; a01 += av0 * bv.y; a02 += av0 * bv.z; a03 += av0 * bv.w;
                a10 += av1 * bv.x; a11 += av1 * bv.y; a12 += av1 * bv.z; a13 += av1 * bv.w;
            }
        }
        int b_ = b0 + 2 * ty;
        float rowv[2][4] = {{a00, a01, a02, a03}, {a10, a11, a12, a13}};
#pragma unroll
        for (int jj = 0; jj < 4; ++jj) {
            int col = c0 + 4 * tx + jj;
            int I = col >> 7, p = col & 127;
            Tn[I * 16384 + p * 128 + b_] = rowv[0][jj];
            Tn[I * 16384 + p * 128 + b_ + 1] = rowv[1][jj];
        }
    }
}

// ---------------- phase B (512 threads, grid 144) — R11 verbatim ------------
__global__ __launch_bounds__(512) void k_B2(float* __restrict__ ws, int k) {
    __shared__ __align__(16) float sm[8576];
    int bid = blockIdx.x, t = threadIdx.x;
    int z = t >> 8, tl = t & 255;
    int ty = tl >> 4, tx = tl & 15;
    float a00 = 0, a01 = 0, a02 = 0, a03 = 0;
    float a10 = 0, a11 = 0, a12 = 0, a13 = 0;
    float* As = sm + z * 3264;        // [32][34] = 1088
    float* Bs = sm + z * 3264 + 1088; // [32][68] = 2176
    float* red = sm + 6528;           // 2048
    if (bid < 128) {
        int side = bid >> 6;
        int eb = bid & 63;
        int r0 = (eb & 31) * 32;
        int c0 = (eb >> 5) * 64;
        const float* A = ws + (side ? OFF_T2R : OFF_T2L);
        const float* B = ws + (side ? OFF_MR2 : OFF_M2) + k * M2SZ;
        float* C = ws + (side ? OFF_LR : OFF_LL);
        int rr = tl >> 3, kq = tl & 7;
        int kkb0 = tl >> 4, cq0 = tl & 15;
        int kkb1 = (256 + tl) >> 4, cq1 = tl & 15;
        int k0 = (z * 8) * 32;
        float4 pa = *(const float4*)&A[(r0 + rr) * 512 + k0 + kq * 4];
        int row0 = k0 + kkb0, row1 = k0 + kkb1;
        float4 pb0 = *(const float4*)&B[(row0 >> 2) * 512 + (row0 & 3) * 128 + c0 + cq0 * 4];
        float4 pb1 = *(const float4*)&B[(row1 >> 2) * 512 + (row1 & 3) * 128 + c0 + cq1 * 4];
        for (int c = 0; c < 8; ++c) {
            __syncthreads();
            {
                float* dst = &As[kq * 136 + rr];
                dst[0] = pa.x; dst[34] = pa.y; dst[68] = pa.z; dst[102] = pa.w;
                *(float4*)&Bs[kkb0 * 68 + cq0 * 4] = pb0;
                *(float4*)&Bs[kkb1 * 68 + cq1 * 4] = pb1;
            }
            if (c < 7) {
                int kn = (z * 8 + c + 1) * 32;
                pa = *(const float4*)&A[(r0 + rr) * 512 + kn + kq * 4];
                int r0n = kn + kkb0, r1n = kn + kkb1;
                pb0 = *(const float4*)&B[(r0n >> 2) * 512 + (r0n & 3) * 128 + c0 + cq0 * 4];
                pb1 = *(const float4*)&B[(r1n >> 2) * 512 + (r1n & 3) * 128 + c0 + cq1 * 4];
            }
            __syncthreads();
#pragma unroll 8
            for (int kk = 0; kk < 32; ++kk) {
                float av0 = As[kk * 34 + 2 * ty], av1 = As[kk * 34 + 2 * ty + 1];
                float4 bv = *(float4*)&Bs[kk * 68 + 4 * tx];
                a00 += av0 * bv.x; a01 += av0 * bv.y; a02 += av0 * bv.z; a03 += av0 * bv.w;
                a10 += av1 * bv.x; a11 += av1 * bv.y; a12 += av1 * bv.z; a13 += av1 * bv.w;
            }
        }
        __syncthreads();
        if (z == 1) {
            float4 v0; v0.x = a00; v0.y = a01; v0.z = a02; v0.w = a03;
            float4 v1; v1.x = a10; v1.y = a11; v1.z = a12; v1.w = a13;
            *(float4*)&red[tl * 8] = v0;
            *(float4*)&red[tl * 8 + 4] = v1;
        }
        __syncthreads();
        if (z == 0) {
            float4 v0 = *(float4*)&red[tl * 8];
            float4 v1 = *(float4*)&red[tl * 8 + 4];
            a00 += v0.x; a01 += v0.y; a02 += v0.z; a03 += v0.w;
            a10 += v1.x; a11 += v1.y; a12 += v1.z; a13 += v1.w;
            int r = r0 + 2 * ty, cc = c0 + 4 * tx;
            float4 w0; w0.x = a00; w0.y = a01; w0.z = a02; w0.w = a03;
            float4 w1; w1.x = a10; w1.y = a11; w1.z = a12; w1.w = a13;
            *(float4*)&C[(r >> 3) * 1024 + (r & 7) * 128 + cc] = w0;
            *(float4*)&C[((r + 1) >> 3) * 1024 + ((r + 1) & 7) * 128 + cc] = w1;
        }
    } else if (bid < 144) {
        int g = bid - 128;               // R11 norm B verbatim
        int side = g >> 3;
        int nn = g & 7;
        int r0 = (nn & 3) * 32;
        int c0 = (nn >> 2) * 64;
        const float* A = ws + (side ? OFF_TNR : OFF_TNL);
        const float* B = ws + (side ? OFF_MR2 : OFF_M2) + k * M2SZ;
        float* C = ws + (side ? OFF_NR : OFF_NL);
        for (int c = 0; c < 8; ++c) {
            int cg = z * 8 + c;
            int Ic = cg >> 2, bc = (cg & 3) * 32;
            __syncthreads();
            {
                int rr = tl >> 3, kq = tl & 7;
                const float4 v = *(const float4*)&A[Ic * 16384 + (r0 + rr) * 128 + bc + kq * 4];
                float* dst = &As[kq * 136 + rr];
                dst[0] = v.x; dst[34] = v.y; dst[68] = v.z; dst[102] = v.w;
            }
#pragma unroll
            for (int u = 0; u < 2; ++u) {
                int e = u * 256 + tl;
                int kk = e >> 4, cq = e & 15;
                const float4 v = *(const float4*)&B[(bc + kk) * 512 + Ic * 128 + c0 + cq * 4];
                *(float4*)&Bs[kk * 68 + cq * 4] = v;
            }
            __syncthreads();
#pragma unroll 8
            for (int kk = 0; kk < 32; ++kk) {
                float av0 = As[kk * 34 + 2 * ty], av1 = As[kk * 34 + 2 * ty + 1];
                float4 bv = *(float4*)&Bs[kk * 68 + 4 * tx];
                a00 += av0 * bv.x; a01 += av0 * bv.y; a02 += av0 * bv.z; a03 += av0 * bv.w;
                a10 += av1 * bv.x; a11 += av1 * bv.y; a12 += av1 * bv.z; a13 += av1 * bv.w;
            }
        }
        __syncthreads();
        if (z == 1) {
            float4 v0; v0.x = a00; v0.y = a01; v0.z = a02; v0.w = a03;
            float4 v1; v1.x = a10; v1.y = a11; v1.z = a12; v1.w = a13;
            *(float4*)&red[tl * 8] = v0;
            *(float4*)&red[tl * 8 + 4] = v1;
        }
        __syncthreads();
        if (z == 0) {
            float4 v0 = *(float4*)&red[tl * 8];
            float4 v1 = *(float4*)&red[tl * 8 + 4];
            a00 += v0.x; a01 += v0.y; a02 += v0.z; a03 += v0.w;
            a10 += v1.x; a11 += v1.y; a12 += v1.z; a13 += v1.w;
            int r = r0 + 2 * ty, cc = c0 + 4 * tx;
            float4 w0; w0.x = a00; w0.y = a01; w0.z = a02; w0.w = a03;
            float4 w1; w1.x = a10; w1.y = a11; w1.z = a12; w1.w = a13;
            *(float4*)&C[r * 128 + cc] = w0;
            *(float4*)&C[(r + 1) * 128 + cc] = w1;
        }
    }
}

// ---------------- dot partials + loss (R11 verbatim) ------------------------
__global__ __launch_bounds__(256) void k_dot(float* __restrict__ ws) {
    __shared__ float se[256], sn[256];
    int bid = blockIdx.x, t = threadIdx.x;
    const float* LL = ws + OFF_LL;
    const float* LR = ws + OFF_LR;
    float e = 0.f;
#pragma unroll
    for (int u = 0; u < 4; ++u) {
        int i = bid * 1024 + u * 256 + t;
        e += LL[i] * LR[i];
    }
    float n = 0.f;
    if (t < 128) {
        int i = bid * 128 + t;
        n = ws[OFF_NL + i] * ws[OFF_NR + i];
    }
    se[t] = e;
    sn[t] = n;
    __syncthreads();
    for (int s = 128; s > 0; s >>= 1) {
        if (t < s) { se[t] += se[t + s]; sn[t] += sn[t + s]; }
        __syncthreads();
    }
    if (t == 0) {
        ws[OFF_PART + bid] = se[0];
        ws[OFF_PARTN + bid] = sn[0];
    }
}

__global__ __launch_bounds__(256) void k_loss(const float* __restrict__ ws,
                                              float* __restrict__ out) {
    __shared__ float se[128], sn[128];
    int t = threadIdx.x;
    if (t < 128) {
        se[t] = ws[OFF_PART + t];
        sn[t] = ws[OFF_PARTN + t];
    }
    __syncthreads();
    for (int s = 64; s > 0; s >>= 1) {
        if (t < s) { se[t] += se[t + s]; sn[t] += sn[t + s]; }
        __syncthreads();
    }
    if (t == 0) {
        float E = se[0], Nm = sn[0];
        out[0] = E;
        out[1] = Nm;
        out[2] = E / Nm;
        out[3] = fmaxf(Nm - 10000.0f, 0.0f);
    }
}

extern "C" void kernel_launch(void* const* d_in, const int* in_sizes, int n_in,
                              void* d_out, int out_size, void* d_ws, size_t ws_size,
                              hipStream_t stream) {
    const float* Min = (const float*)d_in[0];
    const float* Hin = (const float*)d_in[1];
    float* ws = (float*)d_ws;
    float* out = (float*)d_out;
    (void)in_sizes; (void)n_in; (void)out_size; (void)ws_size;

    k_prep1<<<dim3(641), dim3(256), 0, stream>>>(Min, Hin, ws);
    k_prep2<<<dim3(640), dim3(256), 0, stream>>>(ws);
    for (int k = 0; k < HALF2; ++k) {
        k_A2<<<dim3(160), dim3(512), 0, stream>>>(ws, k);
        k_B2<<<dim3(144), dim3(512), 0, stream>>>(ws, k);
    }
    k_dot<<<dim3(128), dim3(256), 0, stream>>>(ws);
    k_loss<<<dim3(1), dim3(256), 0, stream>>>(ws, out);
}

// Round 13
// 385.540 us; speedup vs baseline: 1.1909x; 1.0054x over previous
//
#include <hip/hip_runtime.h>

// VariationalMPS R15: R14 base (386us-class) with eB's sync skeleton halved:
// double-buffered LDS tiles in the energy-B GEMM -> ONE __syncthreads per
// k-chunk (was 2), and the LDS-store + vmcnt drain of chunk c+1 moved AFTER
// compute(c) (was serialized before it). LDS 34->60KB (still 1 block/CU).
// eA (R12-verified acc[8][4] version), norm paths, preps, dot, loss: verbatim.
// Falsified so far: eA-LDS-port model (R14 neutral), block-split (R13 regr),
// deep-restructure (R12 regr). This targets the invariant: barrier overhead.

#define D 128
#define W 8
#define NS 40
#define NPAIR 20
#define HALF2 10
#define MSZ (D * 2 * D)        // 32768
#define HSZ (W * W * 2 * 2)    // 256
#define M2SZ (D * 4 * D)       // 65536  [a][I][c] = a*512+I*128+c
#define H2SZ (W * W * 4 * 4)   // 1024   [w][x][I][J]
#define LSZ (D * W * D)        // 131072 [a][w][b] (= [p][x][q] after B)
#define NSZ (D * D)            // 16384
#define T2SZ (D * W * D * 4)   // 524288 row(p,x)*512 + b*4+J
#define TNSZ (4 * D * D)       // 65536  [I][p][b]

#define OFF_M2 0
#define OFF_MR2 (OFF_M2 + NPAIR * M2SZ)
#define OFF_H2 (OFF_MR2 + HALF2 * M2SZ)
#define OFF_HR2 (OFF_H2 + NPAIR * H2SZ)
#define OFF_LL (OFF_HR2 + HALF2 * H2SZ)
#define OFF_LR (OFF_LL + LSZ)
#define OFF_NL (OFF_LR + LSZ)
#define OFF_NR (OFF_NL + NSZ)
#define OFF_T2L (OFF_NR + NSZ)
#define OFF_T2R (OFF_T2L + T2SZ)
#define OFF_TNL (OFF_T2R + T2SZ)
#define OFF_TNR (OFF_TNL + TNSZ)
#define OFF_PART (OFF_TNR + TNSZ)
#define OFF_PARTN (OFF_PART + 128)

// ---------------- prep1: pair GEMMs M2 (640 blocks) + H2 (block 640) --------
__global__ __launch_bounds__(256) void k_prep1(const float* __restrict__ Min,
                                               const float* __restrict__ Hin,
                                               float* __restrict__ ws) {
    __shared__ float As[32 * 34];
    __shared__ float Bs[32 * 68];
    int bid = blockIdx.x, t = threadIdx.x;
    if (bid < 640) {
        int m = bid >> 5, tile = bid & 31;
        int r0 = (tile & 7) * 32, c0 = (tile >> 3) * 64;
        const float* A = Min + (2 * m) * MSZ;
        const float* B = Min + (2 * m + 1) * MSZ;
        float* C = ws + OFF_M2 + m * M2SZ;
        int ty = t >> 4, tx = t & 15;
        float a00 = 0, a01 = 0, a02 = 0, a03 = 0;
        float a10 = 0, a11 = 0, a12 = 0, a13 = 0;
        for (int c = 0; c < 4; ++c) {
            int k0 = c * 32;
            __syncthreads();
            {
                int rr = t >> 3, kq = t & 7;
                int row = r0 + rr;
                const float4 v = *(const float4*)&A[(row >> 1) * 256 + (row & 1) * 128 + k0 + kq * 4];
                float* dst = &As[kq * 136 + rr];
                dst[0] = v.x; dst[34] = v.y; dst[68] = v.z; dst[102] = v.w;
            }
#pragma unroll
            for (int u = 0; u < 2; ++u) {
                int e = u * 256 + t;
                int kk = e >> 4, cq = e & 15;
                const float4 v = *(const float4*)&B[(k0 + kk) * 256 + c0 + cq * 4];
                *(float4*)&Bs[kk * 68 + cq * 4] = v;
            }
            __syncthreads();
#pragma unroll 8
            for (int kk = 0; kk < 32; ++kk) {
                float2 av = *(float2*)&As[kk * 34 + 2 * ty];
                float4 bv = *(float4*)&Bs[kk * 68 + 4 * tx];
                a00 += av.x * bv.x; a01 += av.x * bv.y; a02 += av.x * bv.z; a03 += av.x * bv.w;
                a10 += av.y * bv.x; a11 += av.y * bv.y; a12 += av.y * bv.z; a13 += av.y * bv.w;
            }
        }
        int r = r0 + 2 * ty, cc = c0 + 4 * tx;
        int a = r >> 1, i2 = cc >> 7, cd = cc & 127;
        float4 v0; v0.x = a00; v0.y = a01; v0.z = a02; v0.w = a03;
        float4 v1; v1.x = a10; v1.y = a11; v1.z = a12; v1.w = a13;
        *(float4*)&C[a * 512 + (0 * 2 + i2) * 128 + cd] = v0;
        *(float4*)&C[a * 512 + (1 * 2 + i2) * 128 + cd] = v1;
    } else {
        for (int idx = t; idx < NPAIR * H2SZ; idx += 256) {
            int m = idx >> 10, r = idx & 1023;
            int w = r >> 7, x = (r >> 4) & 7, I = (r >> 2) & 3, J = r & 3;
            int i1 = I >> 1, i2 = I & 1, j1 = J >> 1, j2 = J & 1;
            const float* Ha = Hin + (2 * m) * HSZ;
            const float* Hb = Hin + (2 * m + 1) * HSZ;
            float s = 0.f;
#pragma unroll
            for (int v = 0; v < 8; ++v)
                s += Ha[w * 32 + v * 4 + i1 * 2 + j1] * Hb[v * 32 + x * 4 + i2 * 2 + j2];
            ws[OFF_H2 + idx] = s;
        }
    }
}

// ---------------- prep2: rev transposes + env init --------------------------
#define PR_MR (HALF2 * M2SZ)
#define PR_HR (PR_MR + HALF2 * H2SZ)
#define PR_TOT (PR_HR + 2 * LSZ + 2 * NSZ)
__global__ __launch_bounds__(256) void k_prep2(float* __restrict__ ws) {
    for (int idx = blockIdx.x * 256 + threadIdx.x; idx < PR_TOT; idx += gridDim.x * 256) {
        if (idx < PR_MR) {
            int kr = idx >> 16, r = idx & 65535;
            int a = r >> 9, I = (r >> 7) & 3, p = r & 127;
            ws[OFF_MR2 + idx] = ws[OFF_M2 + (19 - kr) * M2SZ + p * 512 + I * 128 + a];
        } else if (idx < PR_HR) {
            int e = idx - PR_MR;
            int kr = e >> 10, r = e & 1023;
            int w = r >> 7, x = (r >> 4) & 7, lo = r & 15;
            ws[OFF_HR2 + e] = ws[OFF_H2 + (19 - kr) * H2SZ + x * 128 + w * 16 + lo];
        } else {
            int e = idx - PR_HR;
            int off; float v = 0.f;
            if (e < LSZ)            { off = OFF_LL + e; if (e == 0) v = 1.f; }
            else if (e < 2 * LSZ)   { int r = e - LSZ; off = OFF_LR + r; if (r == (W - 1) * D) v = 1.f; }
            else if (e < 2 * LSZ + NSZ) { int r = e - 2 * LSZ; off = OFF_NL + r; if (r == 0) v = 1.f; }
            else                    { int r = e - 2 * LSZ - NSZ; off = OFF_NR + r; if (r == 0) v = 1.f; }
            ws[off] = v;
        }
    }
}

// ---------------- phase A (512 threads, grid 160) — R14 verbatim ------------
__global__ __launch_bounds__(512) void k_A2(float* __restrict__ ws, int k) {
    __shared__ __align__(16) float sm[17920];
    int bid = blockIdx.x, t = threadIdx.x;
    int z = t >> 8, tl = t & 255;
    if (bid < 128) {
        int side = bid >> 6;
        int eb = bid & 63;
        int b0 = (eb & 7) * 16;
        int p0 = (eb >> 3) * 16;
        const float* Lsrc = ws + (side ? OFF_LR : OFF_LL);
        const float* m2 = ws + (side ? OFF_MR2 : OFF_M2) + k * M2SZ;
        const float* h2 = ws + (side ? OFF_HR2 : OFF_H2) + k * H2SZ;
        float* T2 = ws + (side ? OFF_T2R : OFF_T2L);
        float* Ls = sm + z * 6400;         // [32a][16b][12w-pad] stride 200
        float* ms = sm + 12800 + z * 2048; // [32a][16p][4I]
        float* hs = sm + 16896;            // [32 wI][32 xJ]
#pragma unroll
        for (int u = 0; u < 2; ++u) {   // stage h2
            int e = u * 512 + t;
            int w = e >> 7, I = (e >> 5) & 3, x = (e >> 2) & 7, J = e & 3;
            hs[e] = h2[w * 128 + x * 16 + I * 4 + J];
        }
        int b_l = tl & 15, p_l = tl >> 4;
        float acc[8][4];
#pragma unroll
        for (int w = 0; w < 8; ++w)
#pragma unroll
            for (int I = 0; I < 4; ++I) acc[w][I] = 0.f;
        int la[4], lw[4], lb[4], maa[2], mI[2], mpq[2];
#pragma unroll
        for (int u = 0; u < 4; ++u) {
            int e = u * 256 + tl;
            la[u] = e >> 5; lw[u] = (e >> 2) & 7; lb[u] = e & 3;
        }
#pragma unroll
        for (int u = 0; u < 2; ++u) {
            int e = u * 256 + tl;
            maa[u] = e >> 4; mI[u] = (e >> 2) & 3; mpq[u] = e & 3;
        }
        float4 pl[4], pm[2];
        {
            int a0 = z * 64;
#pragma unroll
            for (int u = 0; u < 4; ++u)
                pl[u] = *(const float4*)&Lsrc[(a0 + la[u]) * 1024 + lw[u] * 128 + b0 + lb[u] * 4];
#pragma unroll
            for (int u = 0; u < 2; ++u)
                pm[u] = *(const float4*)&m2[(a0 + maa[u]) * 512 + mI[u] * 128 + p0 + mpq[u] * 4];
        }
        for (int c = 0; c < 2; ++c) {
            __syncthreads();
#pragma unroll
            for (int u = 0; u < 4; ++u) {
                float* dst = &Ls[la[u] * 200 + lb[u] * 48 + lw[u]];
                dst[0] = pl[u].x; dst[12] = pl[u].y; dst[24] = pl[u].z; dst[36] = pl[u].w;
            }
#pragma unroll
            for (int u = 0; u < 2; ++u) {   // ms[aa][p][I]: scatter over p
                int base = maa[u] * 64 + mpq[u] * 16 + mI[u];
                ms[base] = pm[u].x; ms[base + 4] = pm[u].y;
                ms[base + 8] = pm[u].z; ms[base + 12] = pm[u].w;
            }
            if (c == 0) {
                int a0 = z * 64 + 32;
#pragma unroll
                for (int u = 0; u < 4; ++u)
                    pl[u] = *(const float4*)&Lsrc[(a0 + la[u]) * 1024 + lw[u] * 128 + b0 + lb[u] * 4];
#pragma unroll
                for (int u = 0; u < 2; ++u)
                    pm[u] = *(const float4*)&m2[(a0 + maa[u]) * 512 + mI[u] * 128 + p0 + mpq[u] * 4];
            }
            __syncthreads();
#pragma unroll 4
            for (int aa = 0; aa < 32; ++aa) {
                float4 l0 = *(float4*)&Ls[aa * 200 + b_l * 12];
                float4 l1 = *(float4*)&Ls[aa * 200 + b_l * 12 + 4];
                float4 mv = *(float4*)&ms[aa * 64 + p_l * 4];
                float lv[8] = {l0.x, l0.y, l0.z, l0.w, l1.x, l1.y, l1.z, l1.w};
#pragma unroll
                for (int w = 0; w < 8; ++w) {
                    acc[w][0] += lv[w] * mv.x;
                    acc[w][1] += lv[w] * mv.y;
                    acc[w][2] += lv[w] * mv.z;
                    acc[w][3] += lv[w] * mv.w;
                }
            }
        }
        // reduce z1 -> z0 (red aliases Ls region, dead after sync)
        __syncthreads();
        float* red = sm;
        if (z == 1) {
#pragma unroll
            for (int w = 0; w < 8; ++w) {
                float4 v; v.x = acc[w][0]; v.y = acc[w][1]; v.z = acc[w][2]; v.w = acc[w][3];
                *(float4*)&red[tl * 32 + w * 4] = v;
            }
        }
        __syncthreads();
        if (z == 0) {
#pragma unroll
            for (int w = 0; w < 8; ++w) {
                float4 v = *(float4*)&red[tl * 32 + w * 4];
                acc[w][0] += v.x; acc[w][1] += v.y; acc[w][2] += v.z; acc[w][3] += v.w;
            }
            float o[32];
#pragma unroll
            for (int xJ = 0; xJ < 32; ++xJ) o[xJ] = 0.f;
#pragma unroll
            for (int wI = 0; wI < 32; ++wI) {
                float tv = acc[wI >> 2][wI & 3];
#pragma unroll
                for (int xJ = 0; xJ < 32; ++xJ) o[xJ] += tv * hs[wI * 32 + xJ];
            }
            int b = b0 + b_l, p = p0 + p_l;
#pragma unroll
            for (int x = 0; x < 8; ++x) {
                float4 v; v.x = o[x * 4]; v.y = o[x * 4 + 1];
                v.z = o[x * 4 + 2]; v.w = o[x * 4 + 3];
                *(float4*)&T2[p * 4096 + x * 512 + b * 4] = v;
            }
        }
    } else {
        int g = (bid - 128) * 2 + z;     // 0..63 (R11 norm A verbatim)
        int side = g >> 5;
        int nn = g & 31;
        int b0 = (nn & 3) * 32;
        int c0 = (nn >> 2) * 64;
        const float* Nsrc = ws + (side ? OFF_NR : OFF_NL);
        const float* m2 = ws + (side ? OFF_MR2 : OFF_M2) + k * M2SZ;
        float* Tn = ws + (side ? OFF_TNR : OFF_TNL);
        float* As = sm + z * 3264;       // [32][33]
        float* Bs = sm + z * 3264 + 1056; // [32][68]
        int ty = tl >> 4, tx = tl & 15;
        float a00 = 0, a01 = 0, a02 = 0, a03 = 0;
        float a10 = 0, a11 = 0, a12 = 0, a13 = 0;
        for (int c = 0; c < 4; ++c) {
            int a0 = c * 32;
            __syncthreads();
#pragma unroll
            for (int u = 0; u < 4; ++u) {
                int e = u * 256 + tl;
                int kk = e >> 5, col = e & 31;
                As[kk * 33 + col] = Nsrc[(a0 + kk) * 128 + b0 + col];
            }
#pragma unroll
            for (int u = 0; u < 8; ++u) {
                int e = u * 256 + tl;
                int kk = e >> 6, col = e & 63;
                Bs[kk * 68 + col] = m2[(a0 + kk) * 512 + c0 + col];
            }
            __syncthreads();
#pragma unroll 8
            for (int kk = 0; kk < 32; ++kk) {
                float av0 = As[kk * 33 + 2 * ty], av1 = As[kk * 33 + 2 * ty + 1];
                float4 bv = *(float4*)&Bs[kk * 68 + 4 * tx];
                a00 += av0 * bv.x; a01 += av0 * bv.y; a02 += av0 * bv.z; a03 += av0 * bv.w;
                a10 += av1 * bv.x; a11 += av1 * bv.y; a12 += av1 * bv.z; a13 += av1 * bv.w;
            }
        }
        int b_ = b0 + 2 * ty;
        float rowv[2][4] = {{a00, a01, a02, a03}, {a10, a11, a12, a13}};
#pragma unroll
        for (int jj = 0; jj < 4; ++jj) {
            int col = c0 + 4 * tx + jj;
            int I = col >> 7, p = col & 127;
            Tn[I * 16384 + p * 128 + b_] = rowv[0][jj];
            Tn[I * 16384 + p * 128 + b_ + 1] = rowv[1][jj];
        }
    }
}

// ---------------- phase B (512 threads, grid 144) ---------------------------
// Energy blocks 0..127: R11 inner loop with DOUBLE-BUFFERED LDS: one
// __syncthreads per chunk (was 2); store(c+1)+vmcnt drain after compute(c).
// Norm blocks 128..143: R11 verbatim.
__global__ __launch_bounds__(512) void k_B2(float* __restrict__ ws, int k) {
    __shared__ __align__(16) float sm[15104];
    int bid = blockIdx.x, t = threadIdx.x;
    int z = t >> 8, tl = t & 255;
    int ty = tl >> 4, tx = tl & 15;
    float a00 = 0, a01 = 0, a02 = 0, a03 = 0;
    float a10 = 0, a11 = 0, a12 = 0, a13 = 0;
    if (bid < 128) {
        int side = bid >> 6;
        int eb = bid & 63;
        int r0 = (eb & 31) * 32;
        int c0 = (eb >> 5) * 64;
        const float* A = ws + (side ? OFF_T2R : OFF_T2L);
        const float* B = ws + (side ? OFF_MR2 : OFF_M2) + k * M2SZ;
        float* C = ws + (side ? OFF_LR : OFF_LL);
        float* buf0 = sm + z * 6528;          // As 1088 + Bs 2176 = 3264
        float* buf1 = sm + z * 6528 + 3264;
        float* red = sm + 13056;              // 2048
        int rr = tl >> 3, kq = tl & 7;
        int kkb0 = tl >> 4, cq0 = tl & 15;
        int kkb1 = (256 + tl) >> 4, cq1 = tl & 15;
        float4 pa, pb0, pb1;
        {   // chunk 0: load + store into buf0
            int k0 = (z * 8) * 32;
            pa = *(const float4*)&A[(r0 + rr) * 512 + k0 + kq * 4];
            int row0 = k0 + kkb0, row1 = k0 + kkb1;
            pb0 = *(const float4*)&B[(row0 >> 2) * 512 + (row0 & 3) * 128 + c0 + cq0 * 4];
            pb1 = *(const float4*)&B[(row1 >> 2) * 512 + (row1 & 3) * 128 + c0 + cq1 * 4];
            float* dst = &buf0[kq * 136 + rr];
            dst[0] = pa.x; dst[34] = pa.y; dst[68] = pa.z; dst[102] = pa.w;
            *(float4*)&buf0[1088 + kkb0 * 68 + cq0 * 4] = pb0;
            *(float4*)&buf0[1088 + kkb1 * 68 + cq1 * 4] = pb1;
        }
        __syncthreads();
        for (int c = 0; c < 8; ++c) {
            float* cur = (c & 1) ? buf1 : buf0;
            if (c < 7) {   // prefetch chunk c+1 (waits land before the store)
                int kn = (z * 8 + c + 1) * 32;
                pa = *(const float4*)&A[(r0 + rr) * 512 + kn + kq * 4];
                int r0n = kn + kkb0, r1n = kn + kkb1;
                pb0 = *(const float4*)&B[(r0n >> 2) * 512 + (r0n & 3) * 128 + c0 + cq0 * 4];
                pb1 = *(const float4*)&B[(r1n >> 2) * 512 + (r1n & 3) * 128 + c0 + cq1 * 4];
            }
#pragma unroll 8
            for (int kk = 0; kk < 32; ++kk) {
                float av0 = cur[kk * 34 + 2 * ty], av1 = cur[kk * 34 + 2 * ty + 1];
                float4 bv = *(float4*)&cur[1088 + kk * 68 + 4 * tx];
                a00 += av0 * bv.x; a01 += av0 * bv.y; a02 += av0 * bv.z; a03 += av0 * bv.w;
                a10 += av1 * bv.x; a11 += av1 * bv.y; a12 += av1 * bv.z; a13 += av1 * bv.w;
            }
            if (c < 7) {   // store into the other buffer, ONE barrier per chunk
                float* nxt = (c & 1) ? buf0 : buf1;
                float* dst = &nxt[kq * 136 + rr];
                dst[0] = pa.x; dst[34] = pa.y; dst[68] = pa.z; dst[102] = pa.w;
                *(float4*)&nxt[1088 + kkb0 * 68 + cq0 * 4] = pb0;
                *(float4*)&nxt[1088 + kkb1 * 68 + cq1 * 4] = pb1;
                __syncthreads();
            }
        }
        __syncthreads();
        if (z == 1) {
            float4 v0; v0.x = a00; v0.y = a01; v0.z = a02; v0.w = a03;
            float4 v1; v1.x = a10; v1.y = a11; v1.z = a12; v1.w = a13;
            *(float4*)&red[tl * 8] = v0;
            *(float4*)&red[tl * 8 + 4] = v1;
        }
        __syncthreads();
        if (z == 0) {
            float4 v0 = *(float4*)&red[tl * 8];
            float4 v1 = *(float4*)&red[tl * 8 + 4];
            a00 += v0.x; a01 += v0.y; a02 += v0.z; a03 += v0.w;
            a10 += v1.x; a11 += v1.y; a12 += v1.z; a13 += v1.w;
            int r = r0 + 2 * ty, cc = c0 + 4 * tx;
            float4 w0; w0.x = a00; w0.y = a01; w0.z = a02; w0.w = a03;
            float4 w1; w1.x = a10; w1.y = a11; w1.z = a12; w1.w = a13;
            *(float4*)&C[(r >> 3) * 1024 + (r & 7) * 128 + cc] = w0;
            *(float4*)&C[((r + 1) >> 3) * 1024 + ((r + 1) & 7) * 128 + cc] = w1;
        }
    } else if (bid < 144) {
        float* As = sm + z * 3264;        // [32][34] = 1088 (R11 norm B verbatim)
        float* Bs = sm + z * 3264 + 1088; // [32][68] = 2176
        float* red = sm + 6528;           // 2048
        int g = bid - 128;
        int side = g >> 3;
        int nn = g & 7;
        int r0 = (nn & 3) * 32;
        int c0 = (nn >> 2) * 64;
        const float* A = ws + (side ? OFF_TNR : OFF_TNL);
        const float* B = ws + (side ? OFF_MR2 : OFF_M2) + k * M2SZ;
        float* C = ws + (side ? OFF_NR : OFF_NL);
        for (int c = 0; c < 8; ++c) {
            int cg = z * 8 + c;
            int Ic = cg >> 2, bc = (cg & 3) * 32;
            __syncthreads();
            {
                int rr = tl >> 3, kq = tl & 7;
                const float4 v = *(const float4*)&A[Ic * 16384 + (r0 + rr) * 128 + bc + kq * 4];
                float* dst = &As[kq * 136 + rr];
                dst[0] = v.x; dst[34] = v.y; dst[68] = v.z; dst[102] = v.w;
            }
#pragma unroll
            for (int u = 0; u < 2; ++u) {
                int e = u * 256 + tl;
                int kk = e >> 4, cq = e & 15;
                const float4 v = *(const float4*)&B[(bc + kk) * 512 + Ic * 128 + c0 + cq * 4];
                *(float4*)&Bs[kk * 68 + cq * 4] = v;
            }
            __syncthreads();
#pragma unroll 8
            for (int kk = 0; kk < 32; ++kk) {
                float av0 = As[kk * 34 + 2 * ty], av1 = As[kk * 34 + 2 * ty + 1];
                float4 bv = *(float4*)&Bs[kk * 68 + 4 * tx];
                a00 += av0 * bv.x; a01 += av0 * bv.y; a02 += av0 * bv.z; a03 += av0 * bv.w;
                a10 += av1 * bv.x; a11 += av1 * bv.y; a12 += av1 * bv.z; a13 += av1 * bv.w;
            }
        }
        __syncthreads();
        if (z == 1) {
            float4 v0; v0.x = a00; v0.y = a01; v0.z = a02; v0.w = a03;
            float4 v1; v1.x = a10; v1.y = a11; v1.z = a12; v1.w = a13;
            *(float4*)&red[tl * 8] = v0;
            *(float4*)&red[tl * 8 + 4] = v1;
        }
        __syncthreads();
        if (z == 0) {
            float4 v0 = *(float4*)&red[tl * 8];
            float4 v1 = *(float4*)&red[tl * 8 + 4];
            a00 += v0.x; a01 += v0.y; a02 += v0.z; a03 += v0.w;
            a10 += v1.x; a11 += v1.y; a12 += v1.z; a13 += v1.w;
            int r = r0 + 2 * ty, cc = c0 + 4 * tx;
            float4 w0; w0.x = a00; w0.y = a01; w0.z = a02; w0.w = a03;
            float4 w1; w1.x = a10; w1.y = a11; w1.z = a12; w1.w = a13;
            *(float4*)&C[r * 128 + cc] = w0;
            *(float4*)&C[(r + 1) * 128 + cc] = w1;
        }
    }
}

// ---------------- dot partials + loss (R11 verbatim) ------------------------
__global__ __launch_bounds__(256) void k_dot(float* __restrict__ ws) {
    __shared__ float se[256], sn[256];
    int bid = blockIdx.x, t = threadIdx.x;
    const float* LL = ws + OFF_LL;
    const float* LR = ws + OFF_LR;
    float e = 0.f;
#pragma unroll
    for (int u = 0; u < 4; ++u) {
        int i = bid * 1024 + u * 256 + t;
        e += LL[i] * LR[i];
    }
    float n = 0.f;
    if (t < 128) {
        int i = bid * 128 + t;
        n = ws[OFF_NL + i] * ws[OFF_NR + i];
    }
    se[t] = e;
    sn[t] = n;
    __syncthreads();
    for (int s = 128; s > 0; s >>= 1) {
        if (t < s) { se[t] += se[t + s]; sn[t] += sn[t + s]; }
        __syncthreads();
    }
    if (t == 0) {
        ws[OFF_PART + bid] = se[0];
        ws[OFF_PARTN + bid] = sn[0];
    }
}

__global__ __launch_bounds__(256) void k_loss(const float* __restrict__ ws,
                                              float* __restrict__ out) {
    __shared__ float se[128], sn[128];
    int t = threadIdx.x;
    if (t < 128) {
        se[t] = ws[OFF_PART + t];
        sn[t] = ws[OFF_PARTN + t];
    }
    __syncthreads();
    for (int s = 64; s > 0; s >>= 1) {
        if (t < s) { se[t] += se[t + s]; sn[t] += sn[t + s]; }
        __syncthreads();
    }
    if (t == 0) {
        float E = se[0], Nm = sn[0];
        out[0] = E;
        out[1] = Nm;
        out[2] = E / Nm;
        out[3] = fmaxf(Nm - 10000.0f, 0.0f);
    }
}

extern "C" void kernel_launch(void* const* d_in, const int* in_sizes, int n_in,
                              void* d_out, int out_size, void* d_ws, size_t ws_size,
                              hipStream_t stream) {
    const float* Min = (const float*)d_in[0];
    const float* Hin = (const float*)d_in[1];
    float* ws = (float*)d_ws;
    float* out = (float*)d_out;
    (void)in_sizes; (void)n_in; (void)out_size; (void)ws_size;

    k_prep1<<<dim3(641), dim3(256), 0, stream>>>(Min, Hin, ws);
    k_prep2<<<dim3(640), dim3(256), 0, stream>>>(ws);
    for (int k = 0; k < HALF2; ++k) {
        k_A2<<<dim3(160), dim3(512), 0, stream>>>(ws, k);
        k_B2<<<dim3(144), dim3(512), 0, stream>>>(ws, k);
    }
    k_dot<<<dim3(128), dim3(256), 0, stream>>>(ws);
    k_loss<<<dim3(1), dim3(256), 0, stream>>>(ws, out);
}